// Round 7
// baseline (231.042 us; speedup 1.0000x reference)
//
#include <hip/hip_runtime.h>
#include <hip/hip_bf16.h>
#include <hip/hip_fp16.h>
#include <cstddef>
#include <cstdint>

typedef __attribute__((ext_vector_type(8))) short bf16x8;
typedef __attribute__((ext_vector_type(4))) float f32x4;

#define MFMA16(a, b, c) __builtin_amdgcn_mfma_f32_16x16x32_bf16((a), (b), (c), 0, 0, 0)

static constexpr int B = 4, S = 512, HID = 768, NH = 12, HD = 64;
static constexpr int QKV_N = B * NH * S * HD;
static constexpr size_t SCORES_N = (size_t)B * NH * S * S;

__device__ __forceinline__ short f2bf(float f) {
  unsigned u = __builtin_bit_cast(unsigned, f);
  u += 0x7FFFu + ((u >> 16) & 1u);
  return (short)(u >> 16);
}
__device__ __forceinline__ float h2f(short s) {
  __half h = __builtin_bit_cast(__half, (unsigned short)s);
  return __half2float(h);
}
__device__ __forceinline__ bf16x8 ld_cvt8(const float* __restrict__ p) {
  float4 a = *reinterpret_cast<const float4*>(p);
  float4 b = *reinterpret_cast<const float4*>(p + 4);
  bf16x8 r;
  r[0] = f2bf(a.x); r[1] = f2bf(a.y); r[2] = f2bf(a.z); r[3] = f2bf(a.w);
  r[4] = f2bf(b.x); r[5] = f2bf(b.y); r[6] = f2bf(b.z); r[7] = f2bf(b.w);
  return r;
}
// nontemporal 16B load as native ext-vector (HIP float4 rejected by builtin)
__device__ __forceinline__ f32x4 ld4nt(const float* p) {
  return __builtin_nontemporal_load(reinterpret_cast<const f32x4*>(p));
}
__device__ __forceinline__ bf16x8 cvt8(f32x4 a, f32x4 b) {
  bf16x8 r;
  r[0] = f2bf(a[0]); r[1] = f2bf(a[1]); r[2] = f2bf(a[2]); r[3] = f2bf(a[3]);
  r[4] = f2bf(b[0]); r[5] = f2bf(b[1]); r[6] = f2bf(b[2]); r[7] = f2bf(b[3]);
  return r;
}

// ---------------------------------------------------------------------------
// K1: fused QKV projection.
//   mat 0 (q): normal layout [b][h][i][d] bf16 + FUSED qr = 0.125*q@Wr^T
//   mat 1 (k): normal layout
//   mat 2 (v): TRANSPOSED vT[b][h][d][j] bf16 (for LDS-free PV)
// ---------------------------------------------------------------------------
__global__ __launch_bounds__(256) void k_qkv(
    const float* __restrict__ x,
    const float* __restrict__ Wq, const float* __restrict__ bq,
    const float* __restrict__ Wk, const float* __restrict__ bk,
    const float* __restrict__ Wv, const float* __restrict__ bv,
    const float* __restrict__ Wr,
    short* __restrict__ qkv, short* __restrict__ qrb, short* __restrict__ vT) {
  __shared__ short As[64 * 40];
  __shared__ short Bs[64 * 40];
  __shared__ short qs[64 * 72];   // q-tile re-stage for fused qr (mat 0 only)
  const int m0 = blockIdx.x * 64;
  const int nt = blockIdx.y;
  const int mat = nt / 12;
  const int nc0 = (nt % 12) * 64;
  const float* __restrict__ W    = (mat == 0) ? Wq : (mat == 1) ? Wk : Wv;
  const float* __restrict__ bias = (mat == 0) ? bq : (mat == 1) ? bk : bv;
  short* __restrict__ outp = qkv + (size_t)mat * QKV_N;
  const int t = threadIdx.x;
  const int w = t >> 6, lane = t & 63;
  const int wm = (w >> 1) * 32, wn = (w & 1) * 32;
  const int lr = lane & 15, lk = lane >> 4;
  f32x4 acc[2][2] = {};
  for (int kk = 0; kk < 768; kk += 32) {
#pragma unroll
    for (int it = 0; it < 2; ++it) {
      int f = it * 256 + t;
      {
        int r = f >> 3, c4 = f & 7;
        float4 v = *reinterpret_cast<const float4*>(x + (size_t)(m0 + r) * 768 + kk + c4 * 4);
        short* d = &As[r * 40 + c4 * 4];
        d[0] = f2bf(v.x); d[1] = f2bf(v.y); d[2] = f2bf(v.z); d[3] = f2bf(v.w);
      }
      {
        int kr = f >> 4, c4 = f & 15;
        float4 v = *reinterpret_cast<const float4*>(W + (size_t)(kk + kr) * 768 + nc0 + c4 * 4);
        int c = c4 * 4;
        Bs[(c + 0) * 40 + kr] = f2bf(v.x);
        Bs[(c + 1) * 40 + kr] = f2bf(v.y);
        Bs[(c + 2) * 40 + kr] = f2bf(v.z);
        Bs[(c + 3) * 40 + kr] = f2bf(v.w);
      }
    }
    __syncthreads();
    bf16x8 a0 = *reinterpret_cast<const bf16x8*>(&As[(wm + lr) * 40 + lk * 8]);
    bf16x8 a1 = *reinterpret_cast<const bf16x8*>(&As[(wm + 16 + lr) * 40 + lk * 8]);
    bf16x8 b0 = *reinterpret_cast<const bf16x8*>(&Bs[(wn + lr) * 40 + lk * 8]);
    bf16x8 b1 = *reinterpret_cast<const bf16x8*>(&Bs[(wn + 16 + lr) * 40 + lk * 8]);
    acc[0][0] = MFMA16(a0, b0, acc[0][0]);
    acc[0][1] = MFMA16(a0, b1, acc[0][1]);
    acc[1][0] = MFMA16(a1, b0, acc[1][0]);
    acc[1][1] = MFMA16(a1, b1, acc[1][1]);
    __syncthreads();
  }
  const int b_ = m0 >> 9;       // batch (tile never straddles b: 512 % 64 == 0)
  if (mat == 2) {
    // v: write transposed vT[b][h][d][j]
#pragma unroll
    for (int mf = 0; mf < 2; ++mf)
#pragma unroll
      for (int nf = 0; nf < 2; ++nf) {
        int col = nc0 + wn + nf * 16 + lr;
        float bv_ = bias[col];
        int h = col >> 6, d = col & 63;
#pragma unroll
        for (int reg = 0; reg < 4; ++reg) {
          int j = (m0 + wm + mf * 16 + lk * 4 + reg) & 511;
          vT[((size_t)(b_ * NH + h) * HD + d) * S + j] = f2bf(acc[mf][nf][reg] + bv_);
        }
      }
    return;
  }
  // q / k: normal layout
#pragma unroll
  for (int mf = 0; mf < 2; ++mf)
#pragma unroll
    for (int nf = 0; nf < 2; ++nf) {
      int col = nc0 + wn + nf * 16 + lr;
      float bv_ = bias[col];
      int h = col >> 6, d = col & 63;
#pragma unroll
      for (int reg = 0; reg < 4; ++reg) {
        int mloc = wm + mf * 16 + lk * 4 + reg;
        int i = (m0 + mloc) & 511;
        short qv = f2bf(acc[mf][nf][reg] + bv_);
        outp[(size_t)((b_ * NH + h) * S + i) * HD + d] = qv;
        if (mat == 0) qs[mloc * 72 + d] = qv;
      }
    }
  if (mat == 0) {
    // fused qr = 0.125 * q_tile(64x64) @ Wr^T(64x64), head h0 = nc0/64
    const int h0 = nc0 >> 6;
    __syncthreads();
    f32x4 qacc[2][2] = {};
#pragma unroll
    for (int ks = 0; ks < 2; ++ks) {
      int k0 = ks * 32 + lk * 8;
      bf16x8 a0 = *reinterpret_cast<const bf16x8*>(&qs[(wm + lr) * 72 + k0]);
      bf16x8 a1 = *reinterpret_cast<const bf16x8*>(&qs[(wm + 16 + lr) * 72 + k0]);
      bf16x8 b0 = ld_cvt8(Wr + (size_t)(wn + lr) * 64 + k0);
      bf16x8 b1 = ld_cvt8(Wr + (size_t)(wn + 16 + lr) * 64 + k0);
      qacc[0][0] = MFMA16(a0, b0, qacc[0][0]);
      qacc[0][1] = MFMA16(a0, b1, qacc[0][1]);
      qacc[1][0] = MFMA16(a1, b0, qacc[1][0]);
      qacc[1][1] = MFMA16(a1, b1, qacc[1][1]);
    }
#pragma unroll
    for (int mf = 0; mf < 2; ++mf)
#pragma unroll
      for (int nf = 0; nf < 2; ++nf) {
        int r = wn + nf * 16 + lr;
#pragma unroll
        for (int reg = 0; reg < 4; ++reg) {
          int i = (m0 + wm + mf * 16 + lk * 4 + reg) & 511;
          qrb[((size_t)(b_ * NH + h0) * S + i) * 64 + r] = f2bf(qacc[mf][nf][reg] * 0.125f);
        }
      }
  }
}

// ---------------------------------------------------------------------------
// K3: qk scores -> f16, layout [b][i][h][j].
// ---------------------------------------------------------------------------
__global__ __launch_bounds__(256) void k_qk(const short* __restrict__ q,
                                            const short* __restrict__ kmat,
                                            const float* __restrict__ graph,
                                            const float* __restrict__ endm,
                                            __half* __restrict__ sc) {
  const int j0 = blockIdx.x * 64, i0 = blockIdx.y * 64;
  const int bh = blockIdx.z;
  const int b = bh / NH, hh = bh % NH;
  const short* __restrict__ qp = q + (size_t)(bh * S) * HD;
  const short* __restrict__ kp = kmat + (size_t)(bh * S) * HD;
  const int t = threadIdx.x;
  const int w = t >> 6, lane = t & 63;
  const int wm = (w >> 1) * 32, wn = (w & 1) * 32;
  const int lr = lane & 15, lk = lane >> 4;
  f32x4 acc[2][2] = {};
#pragma unroll
  for (int ks = 0; ks < 2; ++ks) {
    int k0 = ks * 32 + lk * 8;
    bf16x8 a0 = *reinterpret_cast<const bf16x8*>(qp + (size_t)(i0 + wm + lr) * 64 + k0);
    bf16x8 a1 = *reinterpret_cast<const bf16x8*>(qp + (size_t)(i0 + wm + 16 + lr) * 64 + k0);
    bf16x8 b0 = *reinterpret_cast<const bf16x8*>(kp + (size_t)(j0 + wn + lr) * 64 + k0);
    bf16x8 b1 = *reinterpret_cast<const bf16x8*>(kp + (size_t)(j0 + wn + 16 + lr) * 64 + k0);
    acc[0][0] = MFMA16(a0, b0, acc[0][0]);
    acc[0][1] = MFMA16(a0, b1, acc[0][1]);
    acc[1][0] = MFMA16(a1, b0, acc[1][0]);
    acc[1][1] = MFMA16(a1, b1, acc[1][1]);
  }
#pragma unroll
  for (int mf = 0; mf < 2; ++mf)
#pragma unroll
    for (int nf = 0; nf < 2; ++nf) {
      int j = j0 + wn + nf * 16 + lr;
      float e = endm[b * S + j];
#pragma unroll
      for (int reg = 0; reg < 4; ++reg) {
        int i = i0 + wm + mf * 16 + lk * 4 + reg;
        float g = graph[(size_t)(b * S + i) * S + j];
        float s = acc[mf][nf][reg] * 0.125f + (1.0f - g - e) * (-30000.0f);
        sc[(((size_t)b * S + i) * NH + hh) * S + j] = __float2half(s);
      }
    }
}

// ---------------------------------------------------------------------------
// K4: per (b,i): s = sc + qr.rel^T; p = exp(min(s,80)); den-reduce; probs bf16.
// ---------------------------------------------------------------------------
__global__ __launch_bounds__(256) void k_relsm(const short* __restrict__ qrb,
                                               const float* __restrict__ rel,
                                               const __half* __restrict__ sc,
                                               short* __restrict__ probs) {
  __shared__ short sq[16 * 520];   // [h][j] f16 bits
  __shared__ float den_lds[64];
  const int i = blockIdx.x, b = blockIdx.y;
  const int t = threadIdx.x;
  const int w = t >> 6, lane = t & 63;
  const int lr = lane & 15, fq = lane >> 4;
  {
    const short* src = reinterpret_cast<const short*>(sc + ((size_t)(b * S) + i) * NH * S);
    int hh = t >> 4, js = (t & 15) * 32;
    const short* sp = src + (size_t)hh * S + js;
    short* dp = &sq[hh * 520 + js];
#pragma unroll
    for (int c = 0; c < 4; ++c)
      *reinterpret_cast<bf16x8*>(dp + c * 8) = *reinterpret_cast<const bf16x8*>(sp + c * 8);
  }
  const int hA = (lr < NH) ? lr : 0;
  const short* qrow = qrb + ((size_t)(b * NH + hA) * S + i) * 64;
  bf16x8 a0 = *reinterpret_cast<const bf16x8*>(qrow + fq * 8);
  bf16x8 a1 = *reinterpret_cast<const bf16x8*>(qrow + 32 + fq * 8);
  const float* rp = rel + (((size_t)(b * S) + i) * S + (size_t)(w * 128 + lr)) * 64 + fq * 8;
  float p[8][4];
  float den[4] = {0.f, 0.f, 0.f, 0.f};
  f32x4 c0 = ld4nt(rp), c1 = ld4nt(rp + 4), c2 = ld4nt(rp + 32), c3 = ld4nt(rp + 36);
  __syncthreads();
#pragma unroll
  for (int tt = 0; tt < 8; ++tt) {
    f32x4 n0, n1, n2, n3;
    if (tt < 7) {
      const float* rn = rp + (size_t)(tt + 1) * 1024;
      n0 = ld4nt(rn); n1 = ld4nt(rn + 4); n2 = ld4nt(rn + 32); n3 = ld4nt(rn + 36);
    }
    bf16x8 b0 = cvt8(c0, c1), b1 = cvt8(c2, c3);
    f32x4 acc = {};
    acc = MFMA16(a0, b0, acc);
    acc = MFMA16(a1, b1, acc);
    const int j0 = w * 128 + tt * 16;
#pragma unroll
    for (int r = 0; r < 4; ++r) {
      int h = fq * 4 + r;
      float s = acc[r] + h2f(sq[h * 520 + j0 + lr]);
      float pe = __expf(fminf(s, 80.0f));
      den[r] += pe;
      p[tt][r] = pe;
    }
    if (tt < 7) { c0 = n0; c1 = n1; c2 = n2; c3 = n3; }
  }
#pragma unroll
  for (int r = 0; r < 4; ++r) {
    float d = den[r];
    d += __shfl_xor(d, 1); d += __shfl_xor(d, 2);
    d += __shfl_xor(d, 4); d += __shfl_xor(d, 8);
    den[r] = d;
  }
  if (lr == 0) {
#pragma unroll
    for (int r = 0; r < 4; ++r) den_lds[w * 16 + fq * 4 + r] = den[r];
  }
  __syncthreads();
  float invd[4];
#pragma unroll
  for (int r = 0; r < 4; ++r) {
    int h = fq * 4 + r;
    invd[r] = 1.0f / (den_lds[h] + den_lds[16 + h] + den_lds[32 + h] + den_lds[48 + h]);
  }
#pragma unroll
  for (int tt = 0; tt < 8; ++tt) {
    int j0 = w * 128 + tt * 16;
#pragma unroll
    for (int r = 0; r < 4; ++r) {
      int h = fq * 4 + r;
      if (h < NH)
        probs[((size_t)(b * NH + h) * S + i) * S + j0 + lr] = f2bf(p[tt][r] * invd[r]);
    }
  }
}

// ---------------------------------------------------------------------------
// K5: ctx = probs @ v via MFMA, LDS-free (vT[b,h,d,j]).
// ---------------------------------------------------------------------------
__global__ __launch_bounds__(256) void k_pv2(const short* __restrict__ probs,
                                             const short* __restrict__ vT,
                                             float* __restrict__ out) {
  const int i0 = blockIdx.x * 32;
  const int h = blockIdx.y, b = blockIdx.z;
  const short* __restrict__ pp  = probs + (size_t)((b * NH + h) * S) * S;
  const short* __restrict__ vtp = vT + (size_t)((b * NH + h) * HD) * S;
  const int t = threadIdx.x;
  const int w = t >> 6, lane = t & 63;
  const int wm = (w >> 1) * 16, wn = (w & 1) * 32;
  const int lr = lane & 15, lk = lane >> 4;
  f32x4 acc[2] = {};
#pragma unroll
  for (int j0 = 0; j0 < S; j0 += 64) {
#pragma unroll
    for (int ks = 0; ks < 2; ++ks) {
      int k0 = j0 + ks * 32 + lk * 8;
      bf16x8 a0 = *reinterpret_cast<const bf16x8*>(pp + (size_t)(i0 + wm + lr) * S + k0);
      bf16x8 b0 = *reinterpret_cast<const bf16x8*>(vtp + (size_t)(wn + lr) * S + k0);
      bf16x8 b1 = *reinterpret_cast<const bf16x8*>(vtp + (size_t)(wn + 16 + lr) * S + k0);
      acc[0] = MFMA16(a0, b0, acc[0]);
      acc[1] = MFMA16(a0, b1, acc[1]);
    }
  }
#pragma unroll
  for (int nf = 0; nf < 2; ++nf) {
    int d = wn + nf * 16 + lr;
#pragma unroll
    for (int reg = 0; reg < 4; ++reg) {
      int i = i0 + wm + lk * 4 + reg;
      out[((size_t)(b * S) + i) * HID + h * 64 + d] = acc[nf][reg];
    }
  }
}

// ---------------------------------------------------------------------------
// MEASUREMENT ROUND: k_relsm launched TWICE (idempotent -> identical output).
// dur_delta vs round 6 (164.6 us) == true k_relsm duration.
// ---------------------------------------------------------------------------
extern "C" void kernel_launch(void* const* d_in, const int* in_sizes, int n_in,
                              void* d_out, int out_size, void* d_ws, size_t ws_size,
                              hipStream_t stream) {
  const float* x     = (const float*)d_in[0];
  const float* graph = (const float*)d_in[1];
  const float* endm  = (const float*)d_in[2];
  const float* rel   = (const float*)d_in[3];
  const float* Wq = (const float*)d_in[4];  const float* bq = (const float*)d_in[5];
  const float* Wk = (const float*)d_in[6];  const float* bk = (const float*)d_in[7];
  const float* Wv = (const float*)d_in[8];  const float* bv = (const float*)d_in[9];
  const float* Wr = (const float*)d_in[10]; // br dropped: softmax-invariant

  short* qb  = (short*)d_ws;
  short* kb  = qb + QKV_N;
  short* vTb = kb + QKV_N;                          // v transposed [b][h][d][j]
  short* qrb = vTb + QKV_N;
  __half* scores = (__half*)(qrb + QKV_N);          // f16, [b][i][h][j]
  short* probs   = (short*)(scores + SCORES_N);     // bf16, [b][h][i][j]
  const size_t need = (size_t)4 * QKV_N * 2 + SCORES_N * 2 + SCORES_N * 2;
  if (ws_size < need) return;

  k_qkv<<<dim3(32, 36), 256, 0, stream>>>(x, Wq, bq, Wk, bk, Wv, bv, Wr, qb, qrb, vTb);
  k_qk<<<dim3(8, 8, B * NH), 256, 0, stream>>>(qb, kb, graph, endm, scores);
  k_relsm<<<dim3(S, B), 256, 0, stream>>>(qrb, rel, scores, probs);
  k_relsm<<<dim3(S, B), 256, 0, stream>>>(qrb, rel, scores, probs);  // MEASURE: duplicate
  k_pv2<<<dim3(16, NH, B), 256, 0, stream>>>(probs, vTb, (float*)d_out);
}

// Round 8
// 200.708 us; speedup vs baseline: 1.1511x; 1.1511x over previous
//
#include <hip/hip_runtime.h>
#include <hip/hip_bf16.h>
#include <hip/hip_fp16.h>
#include <cstddef>
#include <cstdint>

typedef __attribute__((ext_vector_type(8))) short bf16x8;
typedef __attribute__((ext_vector_type(4))) float f32x4;

#define MFMA16(a, b, c) __builtin_amdgcn_mfma_f32_16x16x32_bf16((a), (b), (c), 0, 0, 0)

static constexpr int B = 4, S = 512, HID = 768, NH = 12, HD = 64;
static constexpr int QKV_N = B * NH * S * HD;              // 1,572,864
static constexpr size_t SCORES_N = (size_t)B * NH * S * S; // 12,582,912
static constexpr int XB_N  = 2048 * 768;                   // 1,572,864
static constexpr int WT_N  = 768 * 768;                    // 589,824

__device__ __forceinline__ short f2bf(float f) {
  unsigned u = __builtin_bit_cast(unsigned, f);
  u += 0x7FFFu + ((u >> 16) & 1u);
  return (short)(u >> 16);
}
__device__ __forceinline__ float h2f(short s) {
  __half h = __builtin_bit_cast(__half, (unsigned short)s);
  return __half2float(h);
}
__device__ __forceinline__ bf16x8 ld_cvt8(const float* __restrict__ p) {
  float4 a = *reinterpret_cast<const float4*>(p);
  float4 b = *reinterpret_cast<const float4*>(p + 4);
  bf16x8 r;
  r[0] = f2bf(a.x); r[1] = f2bf(a.y); r[2] = f2bf(a.z); r[3] = f2bf(a.w);
  r[4] = f2bf(b.x); r[5] = f2bf(b.y); r[6] = f2bf(b.z); r[7] = f2bf(b.w);
  return r;
}
__device__ __forceinline__ f32x4 ld4nt(const float* p) {
  return __builtin_nontemporal_load(reinterpret_cast<const f32x4*>(p));
}
__device__ __forceinline__ bf16x8 cvt8(f32x4 a, f32x4 b) {
  bf16x8 r;
  r[0] = f2bf(a[0]); r[1] = f2bf(a[1]); r[2] = f2bf(a[2]); r[3] = f2bf(a[3]);
  r[4] = f2bf(b[0]); r[5] = f2bf(b[1]); r[6] = f2bf(b[2]); r[7] = f2bf(b[3]);
  return r;
}

// ---------------------------------------------------------------------------
// K0 (prep): role A  blk [0,768)    : x -> xb bf16
//            role B  blk [768,1200) : Wq/Wk/Wv -> WbT[mat][n][k] bf16 (transposed)
//            role C  blk [1200,1212): WqrT[h*64+r][k] = 0.125*(Wq_h @ Wr^T)^T, bqr
// ---------------------------------------------------------------------------
__global__ __launch_bounds__(256) void k_prep(
    const float* __restrict__ x,
    const float* __restrict__ Wq, const float* __restrict__ Wk,
    const float* __restrict__ Wv, const float* __restrict__ Wr,
    const float* __restrict__ bq,
    short* __restrict__ xb, short* __restrict__ WbT,
    short* __restrict__ WqrT, float* __restrict__ bqr) {
  __shared__ short tile[64 * 72];
  const int blk = blockIdx.x;
  const int t = threadIdx.x;
  if (blk < 768) {
    // ---- role A: convert x (8 f32/thread) ----
    size_t base = (size_t)blk * 2048 + t * 8;
    *reinterpret_cast<bf16x8*>(xb + base) = ld_cvt8(x + base);
    return;
  }
  if (blk < 1200) {
    // ---- role B: 64x64 transpose-convert tile ----
    int q = blk - 768;
    int mat = q / 144, rest = q % 144;
    int kt = (rest / 12) * 64, nt = (rest % 12) * 64;
    const float* __restrict__ W = (mat == 0) ? Wq : (mat == 1) ? Wk : Wv;
    int r0 = t >> 2, c0 = (t & 3) * 16;      // row in k-dim, col chunk in n-dim
    const float* src = W + (size_t)(kt + r0) * 768 + nt + c0;
#pragma unroll
    for (int u = 0; u < 16; u += 4) {
      float4 v = *reinterpret_cast<const float4*>(src + u);
      tile[(c0 + u + 0) * 72 + r0] = f2bf(v.x);
      tile[(c0 + u + 1) * 72 + r0] = f2bf(v.y);
      tile[(c0 + u + 2) * 72 + r0] = f2bf(v.z);
      tile[(c0 + u + 3) * 72 + r0] = f2bf(v.w);
    }
    __syncthreads();
    // write out rows n = nt+r0, cols k = kt+c0..+16
    short* dst = WbT + (size_t)mat * WT_N + (size_t)(nt + r0) * 768 + kt + c0;
    *reinterpret_cast<bf16x8*>(dst)     = *reinterpret_cast<const bf16x8*>(&tile[r0 * 72 + c0]);
    *reinterpret_cast<bf16x8*>(dst + 8) = *reinterpret_cast<const bf16x8*>(&tile[r0 * 72 + c0 + 8]);
    return;
  }
  // ---- role C: combined qr weight for head h ----
  const int h = blk - 1200;
  if (t < 64) {
    float s = 0.f;
#pragma unroll
    for (int d = 0; d < 64; ++d) s += bq[h * 64 + d] * Wr[t * 64 + d];
    bqr[h * 64 + t] = 0.125f * s;
  }
  const int w = t >> 6, lane = t & 63;
  const int wm = (w >> 1) * 32, wn = (w & 1) * 32;
  const int lr = lane & 15, lk = lane >> 4;
  for (int kt = 0; kt < 768; kt += 64) {
    f32x4 acc[2][2] = {};
#pragma unroll
    for (int ks = 0; ks < 2; ++ks) {
      int d0 = ks * 32 + lk * 8;
      bf16x8 a0 = ld_cvt8(Wr + (size_t)(wm + lr) * 64 + d0);
      bf16x8 a1 = ld_cvt8(Wr + (size_t)(wm + 16 + lr) * 64 + d0);
      bf16x8 b0 = ld_cvt8(Wq + (size_t)(kt + wn + lr) * 768 + h * 64 + d0);
      bf16x8 b1 = ld_cvt8(Wq + (size_t)(kt + wn + 16 + lr) * 768 + h * 64 + d0);
      acc[0][0] = MFMA16(a0, b0, acc[0][0]);
      acc[0][1] = MFMA16(a0, b1, acc[0][1]);
      acc[1][0] = MFMA16(a1, b0, acc[1][0]);
      acc[1][1] = MFMA16(a1, b1, acc[1][1]);
    }
#pragma unroll
    for (int mf = 0; mf < 2; ++mf)
#pragma unroll
      for (int nf = 0; nf < 2; ++nf) {
        int kcol = kt + wn + nf * 16 + lr;
#pragma unroll
        for (int reg = 0; reg < 4; ++reg) {
          int r = wm + mf * 16 + lk * 4 + reg;
          WqrT[(size_t)(h * 64 + r) * 768 + kcol] = f2bf(0.125f * acc[mf][nf][reg]);
        }
      }
  }
}

// ---------------------------------------------------------------------------
// K1: uniform projection GEMM, LDS-free. M=2048, K=768, N=48 blocks of 64.
//   n-block 0-11: q -> [b][h][i][d];  12-23: k;  24-35: v -> vT[b][h][d][j];
//   36-47: qr (combined weight, scale+bias folded) -> qrb.
// ---------------------------------------------------------------------------
__global__ __launch_bounds__(256) void k_qkv2(
    const short* __restrict__ xb, const short* __restrict__ WbT,
    const short* __restrict__ WqrT,
    const float* __restrict__ bq, const float* __restrict__ bk,
    const float* __restrict__ bv, const float* __restrict__ bqr,
    short* __restrict__ qkv, short* __restrict__ qrb, short* __restrict__ vT) {
  const int m0 = blockIdx.x * 64;
  const int nb = blockIdx.y;
  const int mat = nb / 12, h0 = nb % 12;
  const short* __restrict__ Bp =
      (mat < 3) ? WbT + (size_t)mat * WT_N + (size_t)(h0 * 64) * 768
                : WqrT + (size_t)(h0 * 64) * 768;
  const float* __restrict__ bias =
      (mat == 0) ? bq + h0 * 64 : (mat == 1) ? bk + h0 * 64
      : (mat == 2) ? bv + h0 * 64 : bqr + h0 * 64;
  const int t = threadIdx.x;
  const int w = t >> 6, lane = t & 63;
  const int wm = (w >> 1) * 32, wn = (w & 1) * 32;
  const int lr = lane & 15, lk = lane >> 4;
  const short* ap0 = xb + (size_t)(m0 + wm + lr) * 768 + lk * 8;
  const short* ap1 = xb + (size_t)(m0 + wm + 16 + lr) * 768 + lk * 8;
  const short* bp0 = Bp + (size_t)(wn + lr) * 768 + lk * 8;
  const short* bp1 = Bp + (size_t)(wn + 16 + lr) * 768 + lk * 8;
  f32x4 acc[2][2] = {};
#pragma unroll 2
  for (int kk = 0; kk < 768; kk += 32) {
    bf16x8 a0 = *reinterpret_cast<const bf16x8*>(ap0 + kk);
    bf16x8 a1 = *reinterpret_cast<const bf16x8*>(ap1 + kk);
    bf16x8 b0 = *reinterpret_cast<const bf16x8*>(bp0 + kk);
    bf16x8 b1 = *reinterpret_cast<const bf16x8*>(bp1 + kk);
    acc[0][0] = MFMA16(a0, b0, acc[0][0]);
    acc[0][1] = MFMA16(a0, b1, acc[0][1]);
    acc[1][0] = MFMA16(a1, b0, acc[1][0]);
    acc[1][1] = MFMA16(a1, b1, acc[1][1]);
  }
  const int b_ = m0 >> 9;
#pragma unroll
  for (int mf = 0; mf < 2; ++mf)
#pragma unroll
    for (int nf = 0; nf < 2; ++nf) {
      int d = wn + nf * 16 + lr;      // col within 64
      float bv_ = bias[d];
#pragma unroll
      for (int reg = 0; reg < 4; ++reg) {
        int i = (m0 + wm + mf * 16 + lk * 4 + reg) & 511;
        float val = acc[mf][nf][reg] + bv_;
        if (mat == 2) {
          vT[((size_t)(b_ * NH + h0) * HD + d) * S + i] = f2bf(val);
        } else if (mat == 3) {
          qrb[((size_t)(b_ * NH + h0) * S + i) * 64 + d] = f2bf(val);
        } else {
          qkv[(size_t)mat * QKV_N + (size_t)((b_ * NH + h0) * S + i) * HD + d] = f2bf(val);
        }
      }
    }
}

// ---------------------------------------------------------------------------
// K3: qk scores -> f16, layout [b][i][h][j].
// ---------------------------------------------------------------------------
__global__ __launch_bounds__(256) void k_qk(const short* __restrict__ q,
                                            const short* __restrict__ kmat,
                                            const float* __restrict__ graph,
                                            const float* __restrict__ endm,
                                            __half* __restrict__ sc) {
  const int j0 = blockIdx.x * 64, i0 = blockIdx.y * 64;
  const int bh = blockIdx.z;
  const int b = bh / NH, hh = bh % NH;
  const short* __restrict__ qp = q + (size_t)(bh * S) * HD;
  const short* __restrict__ kp = kmat + (size_t)(bh * S) * HD;
  const int t = threadIdx.x;
  const int w = t >> 6, lane = t & 63;
  const int wm = (w >> 1) * 32, wn = (w & 1) * 32;
  const int lr = lane & 15, lk = lane >> 4;
  f32x4 acc[2][2] = {};
#pragma unroll
  for (int ks = 0; ks < 2; ++ks) {
    int k0 = ks * 32 + lk * 8;
    bf16x8 a0 = *reinterpret_cast<const bf16x8*>(qp + (size_t)(i0 + wm + lr) * 64 + k0);
    bf16x8 a1 = *reinterpret_cast<const bf16x8*>(qp + (size_t)(i0 + wm + 16 + lr) * 64 + k0);
    bf16x8 b0 = *reinterpret_cast<const bf16x8*>(kp + (size_t)(j0 + wn + lr) * 64 + k0);
    bf16x8 b1 = *reinterpret_cast<const bf16x8*>(kp + (size_t)(j0 + wn + 16 + lr) * 64 + k0);
    acc[0][0] = MFMA16(a0, b0, acc[0][0]);
    acc[0][1] = MFMA16(a0, b1, acc[0][1]);
    acc[1][0] = MFMA16(a1, b0, acc[1][0]);
    acc[1][1] = MFMA16(a1, b1, acc[1][1]);
  }
#pragma unroll
  for (int mf = 0; mf < 2; ++mf)
#pragma unroll
    for (int nf = 0; nf < 2; ++nf) {
      int j = j0 + wn + nf * 16 + lr;
      float e = endm[b * S + j];
#pragma unroll
      for (int reg = 0; reg < 4; ++reg) {
        int i = i0 + wm + mf * 16 + lk * 4 + reg;
        float g = graph[(size_t)(b * S + i) * S + j];
        float s = acc[mf][nf][reg] * 0.125f + (1.0f - g - e) * (-30000.0f);
        sc[(((size_t)b * S + i) * NH + hh) * S + j] = __float2half(s);
      }
    }
}

// ---------------------------------------------------------------------------
// K4: per (b,i): s = sc + qr.rel^T; p = exp(min(s,80)); den-reduce; probs bf16.
// ---------------------------------------------------------------------------
__global__ __launch_bounds__(256) void k_relsm(const short* __restrict__ qrb,
                                               const float* __restrict__ rel,
                                               const __half* __restrict__ sc,
                                               short* __restrict__ probs) {
  __shared__ short sq[16 * 520];   // [h][j] f16 bits
  __shared__ float den_lds[64];
  const int i = blockIdx.x, b = blockIdx.y;
  const int t = threadIdx.x;
  const int w = t >> 6, lane = t & 63;
  const int lr = lane & 15, fq = lane >> 4;
  {
    const short* src = reinterpret_cast<const short*>(sc + ((size_t)(b * S) + i) * NH * S);
    int hh = t >> 4, js = (t & 15) * 32;
    const short* sp = src + (size_t)hh * S + js;
    short* dp = &sq[hh * 520 + js];
#pragma unroll
    for (int c = 0; c < 4; ++c)
      *reinterpret_cast<bf16x8*>(dp + c * 8) = *reinterpret_cast<const bf16x8*>(sp + c * 8);
  }
  const int hA = (lr < NH) ? lr : 0;
  const short* qrow = qrb + ((size_t)(b * NH + hA) * S + i) * 64;
  bf16x8 a0 = *reinterpret_cast<const bf16x8*>(qrow + fq * 8);
  bf16x8 a1 = *reinterpret_cast<const bf16x8*>(qrow + 32 + fq * 8);
  const float* rp = rel + (((size_t)(b * S) + i) * S + (size_t)(w * 128 + lr)) * 64 + fq * 8;
  float p[8][4];
  float den[4] = {0.f, 0.f, 0.f, 0.f};
  f32x4 c0 = ld4nt(rp), c1 = ld4nt(rp + 4), c2 = ld4nt(rp + 32), c3 = ld4nt(rp + 36);
  __syncthreads();
#pragma unroll
  for (int tt = 0; tt < 8; ++tt) {
    f32x4 n0, n1, n2, n3;
    if (tt < 7) {
      const float* rn = rp + (size_t)(tt + 1) * 1024;
      n0 = ld4nt(rn); n1 = ld4nt(rn + 4); n2 = ld4nt(rn + 32); n3 = ld4nt(rn + 36);
    }
    bf16x8 b0 = cvt8(c0, c1), b1 = cvt8(c2, c3);
    f32x4 acc = {};
    acc = MFMA16(a0, b0, acc);
    acc = MFMA16(a1, b1, acc);
    const int j0 = w * 128 + tt * 16;
#pragma unroll
    for (int r = 0; r < 4; ++r) {
      int h = fq * 4 + r;
      float s = acc[r] + h2f(sq[h * 520 + j0 + lr]);
      float pe = __expf(fminf(s, 80.0f));
      den[r] += pe;
      p[tt][r] = pe;
    }
    if (tt < 7) { c0 = n0; c1 = n1; c2 = n2; c3 = n3; }
  }
#pragma unroll
  for (int r = 0; r < 4; ++r) {
    float d = den[r];
    d += __shfl_xor(d, 1); d += __shfl_xor(d, 2);
    d += __shfl_xor(d, 4); d += __shfl_xor(d, 8);
    den[r] = d;
  }
  if (lr == 0) {
#pragma unroll
    for (int r = 0; r < 4; ++r) den_lds[w * 16 + fq * 4 + r] = den[r];
  }
  __syncthreads();
  float invd[4];
#pragma unroll
  for (int r = 0; r < 4; ++r) {
    int h = fq * 4 + r;
    invd[r] = 1.0f / (den_lds[h] + den_lds[16 + h] + den_lds[32 + h] + den_lds[48 + h]);
  }
#pragma unroll
  for (int tt = 0; tt < 8; ++tt) {
    int j0 = w * 128 + tt * 16;
#pragma unroll
    for (int r = 0; r < 4; ++r) {
      int h = fq * 4 + r;
      if (h < NH)
        probs[((size_t)(b * NH + h) * S + i) * S + j0 + lr] = f2bf(p[tt][r] * invd[r]);
    }
  }
}

// ---------------------------------------------------------------------------
// K5: ctx = probs @ v via MFMA, LDS-free (vT[b,h,d,j]).
// ---------------------------------------------------------------------------
__global__ __launch_bounds__(256) void k_pv2(const short* __restrict__ probs,
                                             const short* __restrict__ vT,
                                             float* __restrict__ out) {
  const int i0 = blockIdx.x * 32;
  const int h = blockIdx.y, b = blockIdx.z;
  const short* __restrict__ pp  = probs + (size_t)((b * NH + h) * S) * S;
  const short* __restrict__ vtp = vT + (size_t)((b * NH + h) * HD) * S;
  const int t = threadIdx.x;
  const int w = t >> 6, lane = t & 63;
  const int wm = (w >> 1) * 16, wn = (w & 1) * 32;
  const int lr = lane & 15, lk = lane >> 4;
  f32x4 acc[2] = {};
#pragma unroll
  for (int j0 = 0; j0 < S; j0 += 64) {
#pragma unroll
    for (int ks = 0; ks < 2; ++ks) {
      int k0 = j0 + ks * 32 + lk * 8;
      bf16x8 a0 = *reinterpret_cast<const bf16x8*>(pp + (size_t)(i0 + wm + lr) * S + k0);
      bf16x8 b0 = *reinterpret_cast<const bf16x8*>(vtp + (size_t)(wn + lr) * S + k0);
      bf16x8 b1 = *reinterpret_cast<const bf16x8*>(vtp + (size_t)(wn + 16 + lr) * S + k0);
      acc[0] = MFMA16(a0, b0, acc[0]);
      acc[1] = MFMA16(a0, b1, acc[1]);
    }
  }
#pragma unroll
  for (int nf = 0; nf < 2; ++nf) {
    int d = wn + nf * 16 + lr;
#pragma unroll
    for (int reg = 0; reg < 4; ++reg) {
      int i = i0 + wm + lk * 4 + reg;
      out[((size_t)(b * S) + i) * HID + h * 64 + d] = acc[nf][reg];
    }
  }
}

// ---------------------------------------------------------------------------
extern "C" void kernel_launch(void* const* d_in, const int* in_sizes, int n_in,
                              void* d_out, int out_size, void* d_ws, size_t ws_size,
                              hipStream_t stream) {
  const float* x     = (const float*)d_in[0];
  const float* graph = (const float*)d_in[1];
  const float* endm  = (const float*)d_in[2];
  const float* rel   = (const float*)d_in[3];
  const float* Wq = (const float*)d_in[4];  const float* bq = (const float*)d_in[5];
  const float* Wk = (const float*)d_in[6];  const float* bk = (const float*)d_in[7];
  const float* Wv = (const float*)d_in[8];  const float* bv = (const float*)d_in[9];
  const float* Wr = (const float*)d_in[10]; // br dropped: softmax-invariant

  short* xb   = (short*)d_ws;                    // bf16 x            [2048][768]
  short* WbT  = xb + XB_N;                       // bf16 W^T x3       [mat][n][k]
  short* WqrT = WbT + 3 * WT_N;                  // bf16 combined qr  [h*64+r][k]
  float* bqr  = (float*)(WqrT + WT_N);           // f32 [768]
  short* qb   = (short*)(bqr + 768);
  short* kb   = qb + QKV_N;
  short* vTb  = kb + QKV_N;                      // v transposed [b][h][d][j]
  short* qrb  = vTb + QKV_N;
  __half* scores = (__half*)(qrb + QKV_N);       // f16, [b][i][h][j]
  short* probs   = (short*)(scores + SCORES_N);  // bf16, [b][h][i][j]
  const size_t need = (size_t)(XB_N + 4 * WT_N) * 2 + 768 * 4 +
                      (size_t)4 * QKV_N * 2 + SCORES_N * 2 + SCORES_N * 2;
  if (ws_size < need) return;

  k_prep<<<dim3(1212), 256, 0, stream>>>(x, Wq, Wk, Wv, Wr, bq, xb, WbT, WqrT, bqr);
  k_qkv2<<<dim3(32, 48), 256, 0, stream>>>(xb, WbT, WqrT, bq, bk, bv, bqr, qb, qrb, vTb);
  k_qk<<<dim3(8, 8, B * NH), 256, 0, stream>>>(qb, kb, graph, endm, scores);
  k_relsm<<<dim3(S, B), 256, 0, stream>>>(qrb, rel, scores, probs);
  k_pv2<<<dim3(16, NH, B), 256, 0, stream>>>(probs, vTb, (float*)d_out);
}

// Round 9
// 158.536 us; speedup vs baseline: 1.4573x; 1.2660x over previous
//
#include <hip/hip_runtime.h>
#include <hip/hip_bf16.h>
#include <hip/hip_fp16.h>
#include <cstddef>
#include <cstdint>

typedef __attribute__((ext_vector_type(8))) short bf16x8;
typedef __attribute__((ext_vector_type(4))) float f32x4;

#define MFMA16(a, b, c) __builtin_amdgcn_mfma_f32_16x16x32_bf16((a), (b), (c), 0, 0, 0)

static constexpr int B = 4, S = 512, HID = 768, NH = 12, HD = 64;
static constexpr int QKV_N = B * NH * S * HD;
static constexpr size_t SCORES_N = (size_t)B * NH * S * S;

__device__ __forceinline__ short f2bf(float f) {
  unsigned u = __builtin_bit_cast(unsigned, f);
  u += 0x7FFFu + ((u >> 16) & 1u);
  return (short)(u >> 16);
}
__device__ __forceinline__ float h2f(short s) {
  __half h = __builtin_bit_cast(__half, (unsigned short)s);
  return __half2float(h);
}
__device__ __forceinline__ bf16x8 ld_cvt8(const float* __restrict__ p) {
  float4 a = *reinterpret_cast<const float4*>(p);
  float4 b = *reinterpret_cast<const float4*>(p + 4);
  bf16x8 r;
  r[0] = f2bf(a.x); r[1] = f2bf(a.y); r[2] = f2bf(a.z); r[3] = f2bf(a.w);
  r[4] = f2bf(b.x); r[5] = f2bf(b.y); r[6] = f2bf(b.z); r[7] = f2bf(b.w);
  return r;
}
__device__ __forceinline__ f32x4 ld4nt(const float* p) {
  return __builtin_nontemporal_load(reinterpret_cast<const f32x4*>(p));
}
__device__ __forceinline__ bf16x8 cvt8(f32x4 a, f32x4 b) {
  bf16x8 r;
  r[0] = f2bf(a[0]); r[1] = f2bf(a[1]); r[2] = f2bf(a[2]); r[3] = f2bf(a[3]);
  r[4] = f2bf(b[0]); r[5] = f2bf(b[1]); r[6] = f2bf(b[2]); r[7] = f2bf(b[3]);
  return r;
}

// ---------------------------------------------------------------------------
// K1 (round-6 version, reverted from round-8 regression): fused QKV projection.
//   mat 0 (q): [b][h][i][d] bf16 + FUSED qr = 0.125*q@Wr^T
//   mat 1 (k): normal layout
//   mat 2 (v): TRANSPOSED vT[b][h][d][j] bf16
// ---------------------------------------------------------------------------
__global__ __launch_bounds__(256) void k_qkv(
    const float* __restrict__ x,
    const float* __restrict__ Wq, const float* __restrict__ bq,
    const float* __restrict__ Wk, const float* __restrict__ bk,
    const float* __restrict__ Wv, const float* __restrict__ bv,
    const float* __restrict__ Wr,
    short* __restrict__ qkv, short* __restrict__ qrb, short* __restrict__ vT) {
  __shared__ short As[64 * 40];
  __shared__ short Bs[64 * 40];
  __shared__ short qs[64 * 72];
  const int m0 = blockIdx.x * 64;
  const int nt = blockIdx.y;
  const int mat = nt / 12;
  const int nc0 = (nt % 12) * 64;
  const float* __restrict__ W    = (mat == 0) ? Wq : (mat == 1) ? Wk : Wv;
  const float* __restrict__ bias = (mat == 0) ? bq : (mat == 1) ? bk : bv;
  short* __restrict__ outp = qkv + (size_t)mat * QKV_N;
  const int t = threadIdx.x;
  const int w = t >> 6, lane = t & 63;
  const int wm = (w >> 1) * 32, wn = (w & 1) * 32;
  const int lr = lane & 15, lk = lane >> 4;
  f32x4 acc[2][2] = {};
  for (int kk = 0; kk < 768; kk += 32) {
#pragma unroll
    for (int it = 0; it < 2; ++it) {
      int f = it * 256 + t;
      {
        int r = f >> 3, c4 = f & 7;
        float4 v = *reinterpret_cast<const float4*>(x + (size_t)(m0 + r) * 768 + kk + c4 * 4);
        short* d = &As[r * 40 + c4 * 4];
        d[0] = f2bf(v.x); d[1] = f2bf(v.y); d[2] = f2bf(v.z); d[3] = f2bf(v.w);
      }
      {
        int kr = f >> 4, c4 = f & 15;
        float4 v = *reinterpret_cast<const float4*>(W + (size_t)(kk + kr) * 768 + nc0 + c4 * 4);
        int c = c4 * 4;
        Bs[(c + 0) * 40 + kr] = f2bf(v.x);
        Bs[(c + 1) * 40 + kr] = f2bf(v.y);
        Bs[(c + 2) * 40 + kr] = f2bf(v.z);
        Bs[(c + 3) * 40 + kr] = f2bf(v.w);
      }
    }
    __syncthreads();
    bf16x8 a0 = *reinterpret_cast<const bf16x8*>(&As[(wm + lr) * 40 + lk * 8]);
    bf16x8 a1 = *reinterpret_cast<const bf16x8*>(&As[(wm + 16 + lr) * 40 + lk * 8]);
    bf16x8 b0 = *reinterpret_cast<const bf16x8*>(&Bs[(wn + lr) * 40 + lk * 8]);
    bf16x8 b1 = *reinterpret_cast<const bf16x8*>(&Bs[(wn + 16 + lr) * 40 + lk * 8]);
    acc[0][0] = MFMA16(a0, b0, acc[0][0]);
    acc[0][1] = MFMA16(a0, b1, acc[0][1]);
    acc[1][0] = MFMA16(a1, b0, acc[1][0]);
    acc[1][1] = MFMA16(a1, b1, acc[1][1]);
    __syncthreads();
  }
  const int b_ = m0 >> 9;
  if (mat == 2) {
#pragma unroll
    for (int mf = 0; mf < 2; ++mf)
#pragma unroll
      for (int nf = 0; nf < 2; ++nf) {
        int col = nc0 + wn + nf * 16 + lr;
        float bv_ = bias[col];
        int h = col >> 6, d = col & 63;
#pragma unroll
        for (int reg = 0; reg < 4; ++reg) {
          int j = (m0 + wm + mf * 16 + lk * 4 + reg) & 511;
          vT[((size_t)(b_ * NH + h) * HD + d) * S + j] = f2bf(acc[mf][nf][reg] + bv_);
        }
      }
    return;
  }
#pragma unroll
  for (int mf = 0; mf < 2; ++mf)
#pragma unroll
    for (int nf = 0; nf < 2; ++nf) {
      int col = nc0 + wn + nf * 16 + lr;
      float bv_ = bias[col];
      int h = col >> 6, d = col & 63;
#pragma unroll
      for (int reg = 0; reg < 4; ++reg) {
        int mloc = wm + mf * 16 + lk * 4 + reg;
        int i = (m0 + mloc) & 511;
        short qv = f2bf(acc[mf][nf][reg] + bv_);
        outp[(size_t)((b_ * NH + h) * S + i) * HD + d] = qv;
        if (mat == 0) qs[mloc * 72 + d] = qv;
      }
    }
  if (mat == 0) {
    const int h0 = nc0 >> 6;
    __syncthreads();
    f32x4 qacc[2][2] = {};
#pragma unroll
    for (int ks = 0; ks < 2; ++ks) {
      int k0 = ks * 32 + lk * 8;
      bf16x8 a0 = *reinterpret_cast<const bf16x8*>(&qs[(wm + lr) * 72 + k0]);
      bf16x8 a1 = *reinterpret_cast<const bf16x8*>(&qs[(wm + 16 + lr) * 72 + k0]);
      bf16x8 b0 = ld_cvt8(Wr + (size_t)(wn + lr) * 64 + k0);
      bf16x8 b1 = ld_cvt8(Wr + (size_t)(wn + 16 + lr) * 64 + k0);
      qacc[0][0] = MFMA16(a0, b0, qacc[0][0]);
      qacc[0][1] = MFMA16(a0, b1, qacc[0][1]);
      qacc[1][0] = MFMA16(a1, b0, qacc[1][0]);
      qacc[1][1] = MFMA16(a1, b1, qacc[1][1]);
    }
#pragma unroll
    for (int mf = 0; mf < 2; ++mf)
#pragma unroll
      for (int nf = 0; nf < 2; ++nf) {
        int r = wn + nf * 16 + lr;
#pragma unroll
        for (int reg = 0; reg < 4; ++reg) {
          int i = (m0 + wm + mf * 16 + lk * 4 + reg) & 511;
          qrb[((size_t)(b_ * NH + h0) * S + i) * 64 + r] = f2bf(qacc[mf][nf][reg] * 0.125f);
        }
      }
  }
}

// ---------------------------------------------------------------------------
// K3: PURE qk scores -> f16 [b][i][h][j], NO mask (mask moved to relsm).
// Removes the per-head redundant graph reads (201 MB -> 0 here).
// ---------------------------------------------------------------------------
__global__ __launch_bounds__(256) void k_qk(const short* __restrict__ q,
                                            const short* __restrict__ kmat,
                                            __half* __restrict__ sc) {
  const int j0 = blockIdx.x * 64, i0 = blockIdx.y * 64;
  const int bh = blockIdx.z;
  const int b = bh / NH, hh = bh % NH;
  const short* __restrict__ qp = q + (size_t)(bh * S) * HD;
  const short* __restrict__ kp = kmat + (size_t)(bh * S) * HD;
  const int t = threadIdx.x;
  const int w = t >> 6, lane = t & 63;
  const int wm = (w >> 1) * 32, wn = (w & 1) * 32;
  const int lr = lane & 15, lk = lane >> 4;
  f32x4 acc[2][2] = {};
#pragma unroll
  for (int ks = 0; ks < 2; ++ks) {
    int k0 = ks * 32 + lk * 8;
    bf16x8 a0 = *reinterpret_cast<const bf16x8*>(qp + (size_t)(i0 + wm + lr) * 64 + k0);
    bf16x8 a1 = *reinterpret_cast<const bf16x8*>(qp + (size_t)(i0 + wm + 16 + lr) * 64 + k0);
    bf16x8 b0 = *reinterpret_cast<const bf16x8*>(kp + (size_t)(j0 + wn + lr) * 64 + k0);
    bf16x8 b1 = *reinterpret_cast<const bf16x8*>(kp + (size_t)(j0 + wn + 16 + lr) * 64 + k0);
    acc[0][0] = MFMA16(a0, b0, acc[0][0]);
    acc[0][1] = MFMA16(a0, b1, acc[0][1]);
    acc[1][0] = MFMA16(a1, b0, acc[1][0]);
    acc[1][1] = MFMA16(a1, b1, acc[1][1]);
  }
#pragma unroll
  for (int mf = 0; mf < 2; ++mf)
#pragma unroll
    for (int nf = 0; nf < 2; ++nf) {
      int j = j0 + wn + nf * 16 + lr;
#pragma unroll
      for (int reg = 0; reg < 4; ++reg) {
        int i = i0 + wm + mf * 16 + lk * 4 + reg;
        sc[(((size_t)b * S + i) * NH + hh) * S + j] = __float2half(acc[mf][nf][reg] * 0.125f);
      }
    }
}

// ---------------------------------------------------------------------------
// K4: per (b,i): s = sc[h,j] + mask[j] + qr.rel^T; p = exp(min(s,80));
// den-reduce; probs bf16. Mask row staged ONCE per block (graph read 1x,
// not NH x). mask[j] = (1 - g - e)*(-30000); g+e==2 saturates via clamp.
// ---------------------------------------------------------------------------
__global__ __launch_bounds__(256) void k_relsm(const short* __restrict__ qrb,
                                               const float* __restrict__ rel,
                                               const __half* __restrict__ sc,
                                               const float* __restrict__ graph,
                                               const float* __restrict__ endm,
                                               short* __restrict__ probs) {
  __shared__ short sq[16 * 520];    // [h][j] f16 bits
  __shared__ float mask_lds[512];   // (1-g-e)*(-30000)
  __shared__ float den_lds[64];
  const int i = blockIdx.x, b = blockIdx.y;
  const int t = threadIdx.x;
  const int w = t >> 6, lane = t & 63;
  const int lr = lane & 15, fq = lane >> 4;
  {  // stage scores slab (64B/thread)
    const short* src = reinterpret_cast<const short*>(sc + ((size_t)(b * S) + i) * NH * S);
    int hh = t >> 4, js = (t & 15) * 32;
    const short* sp = src + (size_t)hh * S + js;
    short* dp = &sq[hh * 520 + js];
#pragma unroll
    for (int c = 0; c < 4; ++c)
      *reinterpret_cast<bf16x8*>(dp + c * 8) = *reinterpret_cast<const bf16x8*>(sp + c * 8);
  }
  {  // stage mask row: 2 j's per thread
    int j = t * 2;
    float2 g = *reinterpret_cast<const float2*>(graph + ((size_t)b * S + i) * S + j);
    float2 e = *reinterpret_cast<const float2*>(endm + (size_t)b * S + j);
    mask_lds[j]     = (1.0f - g.x - e.x) * (-30000.0f);
    mask_lds[j + 1] = (1.0f - g.y - e.y) * (-30000.0f);
  }
  const int hA = (lr < NH) ? lr : 0;
  const short* qrow = qrb + ((size_t)(b * NH + hA) * S + i) * 64;
  bf16x8 a0 = *reinterpret_cast<const bf16x8*>(qrow + fq * 8);
  bf16x8 a1 = *reinterpret_cast<const bf16x8*>(qrow + 32 + fq * 8);
  const float* rp = rel + (((size_t)(b * S) + i) * S + (size_t)(w * 128 + lr)) * 64 + fq * 8;
  float p[8][4];
  float den[4] = {0.f, 0.f, 0.f, 0.f};
  f32x4 c0 = ld4nt(rp), c1 = ld4nt(rp + 4), c2 = ld4nt(rp + 32), c3 = ld4nt(rp + 36);
  __syncthreads();
#pragma unroll
  for (int tt = 0; tt < 8; ++tt) {
    f32x4 n0, n1, n2, n3;
    if (tt < 7) {
      const float* rn = rp + (size_t)(tt + 1) * 1024;
      n0 = ld4nt(rn); n1 = ld4nt(rn + 4); n2 = ld4nt(rn + 32); n3 = ld4nt(rn + 36);
    }
    bf16x8 b0 = cvt8(c0, c1), b1 = cvt8(c2, c3);
    f32x4 acc = {};
    acc = MFMA16(a0, b0, acc);
    acc = MFMA16(a1, b1, acc);
    const int j0 = w * 128 + tt * 16;
    const float mval = mask_lds[j0 + lr];
#pragma unroll
    for (int r = 0; r < 4; ++r) {
      int h = fq * 4 + r;
      float s = acc[r] + h2f(sq[h * 520 + j0 + lr]) + mval;
      float pe = __expf(fminf(s, 80.0f));
      den[r] += pe;
      p[tt][r] = pe;
    }
    if (tt < 7) { c0 = n0; c1 = n1; c2 = n2; c3 = n3; }
  }
#pragma unroll
  for (int r = 0; r < 4; ++r) {
    float d = den[r];
    d += __shfl_xor(d, 1); d += __shfl_xor(d, 2);
    d += __shfl_xor(d, 4); d += __shfl_xor(d, 8);
    den[r] = d;
  }
  if (lr == 0) {
#pragma unroll
    for (int r = 0; r < 4; ++r) den_lds[w * 16 + fq * 4 + r] = den[r];
  }
  __syncthreads();
  float invd[4];
#pragma unroll
  for (int r = 0; r < 4; ++r) {
    int h = fq * 4 + r;
    invd[r] = 1.0f / (den_lds[h] + den_lds[16 + h] + den_lds[32 + h] + den_lds[48 + h]);
  }
#pragma unroll
  for (int tt = 0; tt < 8; ++tt) {
    int j0 = w * 128 + tt * 16;
#pragma unroll
    for (int r = 0; r < 4; ++r) {
      int h = fq * 4 + r;
      if (h < NH)
        probs[((size_t)(b * NH + h) * S + i) * S + j0 + lr] = f2bf(p[tt][r] * invd[r]);
    }
  }
}

// ---------------------------------------------------------------------------
// K5: ctx = probs @ v via MFMA, LDS-free (vT[b,h,d,j]).
// ---------------------------------------------------------------------------
__global__ __launch_bounds__(256) void k_pv2(const short* __restrict__ probs,
                                             const short* __restrict__ vT,
                                             float* __restrict__ out) {
  const int i0 = blockIdx.x * 32;
  const int h = blockIdx.y, b = blockIdx.z;
  const short* __restrict__ pp  = probs + (size_t)((b * NH + h) * S) * S;
  const short* __restrict__ vtp = vT + (size_t)((b * NH + h) * HD) * S;
  const int t = threadIdx.x;
  const int w = t >> 6, lane = t & 63;
  const int wm = (w >> 1) * 16, wn = (w & 1) * 32;
  const int lr = lane & 15, lk = lane >> 4;
  f32x4 acc[2] = {};
#pragma unroll
  for (int j0 = 0; j0 < S; j0 += 64) {
#pragma unroll
    for (int ks = 0; ks < 2; ++ks) {
      int k0 = j0 + ks * 32 + lk * 8;
      bf16x8 a0 = *reinterpret_cast<const bf16x8*>(pp + (size_t)(i0 + wm + lr) * S + k0);
      bf16x8 b0 = *reinterpret_cast<const bf16x8*>(vtp + (size_t)(wn + lr) * S + k0);
      bf16x8 b1 = *reinterpret_cast<const bf16x8*>(vtp + (size_t)(wn + 16 + lr) * S + k0);
      acc[0] = MFMA16(a0, b0, acc[0]);
      acc[1] = MFMA16(a0, b1, acc[1]);
    }
  }
#pragma unroll
  for (int nf = 0; nf < 2; ++nf) {
    int d = wn + nf * 16 + lr;
#pragma unroll
    for (int reg = 0; reg < 4; ++reg) {
      int i = i0 + wm + lk * 4 + reg;
      out[((size_t)(b * S) + i) * HID + h * 64 + d] = acc[nf][reg];
    }
  }
}

// ---------------------------------------------------------------------------
extern "C" void kernel_launch(void* const* d_in, const int* in_sizes, int n_in,
                              void* d_out, int out_size, void* d_ws, size_t ws_size,
                              hipStream_t stream) {
  const float* x     = (const float*)d_in[0];
  const float* graph = (const float*)d_in[1];
  const float* endm  = (const float*)d_in[2];
  const float* rel   = (const float*)d_in[3];
  const float* Wq = (const float*)d_in[4];  const float* bq = (const float*)d_in[5];
  const float* Wk = (const float*)d_in[6];  const float* bk = (const float*)d_in[7];
  const float* Wv = (const float*)d_in[8];  const float* bv = (const float*)d_in[9];
  const float* Wr = (const float*)d_in[10]; // br dropped: softmax-invariant

  short* qb  = (short*)d_ws;
  short* kb  = qb + QKV_N;
  short* vTb = kb + QKV_N;                       // v transposed [b][h][d][j]
  short* qrb = vTb + QKV_N;
  __half* scores = (__half*)(qrb + QKV_N);       // f16, [b][i][h][j] (unmasked)
  short* probs   = (short*)(scores + SCORES_N);  // bf16, [b][h][i][j]
  const size_t need = (size_t)4 * QKV_N * 2 + SCORES_N * 2 + SCORES_N * 2;
  if (ws_size < need) return;

  k_qkv<<<dim3(32, 36), 256, 0, stream>>>(x, Wq, bq, Wk, bk, Wv, bv, Wr, qb, qrb, vTb);
  k_qk<<<dim3(8, 8, B * NH), 256, 0, stream>>>(qb, kb, scores);
  k_relsm<<<dim3(S, B), 256, 0, stream>>>(qrb, rel, scores, graph, endm, probs);
  k_pv2<<<dim3(16, NH, B), 256, 0, stream>>>(probs, vTb, (float*)d_out);
}

// Round 10
// 152.973 us; speedup vs baseline: 1.5103x; 1.0364x over previous
//
#include <hip/hip_runtime.h>
#include <hip/hip_bf16.h>
#include <hip/hip_fp16.h>
#include <cstddef>
#include <cstdint>

typedef __attribute__((ext_vector_type(8))) short bf16x8;
typedef __attribute__((ext_vector_type(4))) float f32x4;

#define MFMA16(a, b, c) __builtin_amdgcn_mfma_f32_16x16x32_bf16((a), (b), (c), 0, 0, 0)

static constexpr int B = 4, S = 512, HID = 768, NH = 12, HD = 64;
static constexpr int QKV_N = B * NH * S * HD;              // 1,572,864
static constexpr size_t SCORES_N = (size_t)B * NH * S * S; // 12,582,912
static constexpr int XB_N  = 2048 * 768;
static constexpr int WT_N  = 768 * 768;

__device__ __forceinline__ short f2bf(float f) {
  unsigned u = __builtin_bit_cast(unsigned, f);
  u += 0x7FFFu + ((u >> 16) & 1u);
  return (short)(u >> 16);
}
__device__ __forceinline__ float h2f(short s) {
  __half h = __builtin_bit_cast(__half, (unsigned short)s);
  return __half2float(h);
}
__device__ __forceinline__ bf16x8 ld_cvt8(const float* __restrict__ p) {
  float4 a = *reinterpret_cast<const float4*>(p);
  float4 b = *reinterpret_cast<const float4*>(p + 4);
  bf16x8 r;
  r[0] = f2bf(a.x); r[1] = f2bf(a.y); r[2] = f2bf(a.z); r[3] = f2bf(a.w);
  r[4] = f2bf(b.x); r[5] = f2bf(b.y); r[6] = f2bf(b.z); r[7] = f2bf(b.w);
  return r;
}
__device__ __forceinline__ f32x4 ld4nt(const float* p) {
  return __builtin_nontemporal_load(reinterpret_cast<const f32x4*>(p));
}
__device__ __forceinline__ bf16x8 cvt8(f32x4 a, f32x4 b) {
  bf16x8 r;
  r[0] = f2bf(a[0]); r[1] = f2bf(a[1]); r[2] = f2bf(a[2]); r[3] = f2bf(a[3]);
  r[4] = f2bf(b[0]); r[5] = f2bf(b[1]); r[6] = f2bf(b[2]); r[7] = f2bf(b[3]);
  return r;
}

// ---------------------------------------------------------------------------
// K0 (prep, verified round 8): role A blk [0,768): x -> xb bf16
//   role B blk [768,1200): Wq/Wk/Wv -> WbT[mat][n][k] bf16 (transposed)
//   role C blk [1200,1212): WqrT[h*64+r][k] = 0.125*(Wq_h @ Wr^T)^T, bqr
// ---------------------------------------------------------------------------
__global__ __launch_bounds__(256) void k_prep(
    const float* __restrict__ x,
    const float* __restrict__ Wq, const float* __restrict__ Wk,
    const float* __restrict__ Wv, const float* __restrict__ Wr,
    const float* __restrict__ bq,
    short* __restrict__ xb, short* __restrict__ WbT,
    short* __restrict__ WqrT, float* __restrict__ bqr) {
  __shared__ short tile[64 * 72];
  const int blk = blockIdx.x;
  const int t = threadIdx.x;
  if (blk < 768) {
    size_t base = (size_t)blk * 2048 + t * 8;
    *reinterpret_cast<bf16x8*>(xb + base) = ld_cvt8(x + base);
    return;
  }
  if (blk < 1200) {
    int q = blk - 768;
    int mat = q / 144, rest = q % 144;
    int kt = (rest / 12) * 64, nt = (rest % 12) * 64;
    const float* __restrict__ W = (mat == 0) ? Wq : (mat == 1) ? Wk : Wv;
    int r0 = t >> 2, c0 = (t & 3) * 16;
    const float* src = W + (size_t)(kt + r0) * 768 + nt + c0;
#pragma unroll
    for (int u = 0; u < 16; u += 4) {
      float4 v = *reinterpret_cast<const float4*>(src + u);
      tile[(c0 + u + 0) * 72 + r0] = f2bf(v.x);
      tile[(c0 + u + 1) * 72 + r0] = f2bf(v.y);
      tile[(c0 + u + 2) * 72 + r0] = f2bf(v.z);
      tile[(c0 + u + 3) * 72 + r0] = f2bf(v.w);
    }
    __syncthreads();
    short* dst = WbT + (size_t)mat * WT_N + (size_t)(nt + r0) * 768 + kt + c0;
    *reinterpret_cast<bf16x8*>(dst)     = *reinterpret_cast<const bf16x8*>(&tile[r0 * 72 + c0]);
    *reinterpret_cast<bf16x8*>(dst + 8) = *reinterpret_cast<const bf16x8*>(&tile[r0 * 72 + c0 + 8]);
    return;
  }
  const int h = blk - 1200;
  if (t < 64) {
    float s = 0.f;
#pragma unroll
    for (int d = 0; d < 64; ++d) s += bq[h * 64 + d] * Wr[t * 64 + d];
    bqr[h * 64 + t] = 0.125f * s;
  }
  const int w = t >> 6, lane = t & 63;
  const int wm = (w >> 1) * 32, wn = (w & 1) * 32;
  const int lr = lane & 15, lk = lane >> 4;
  for (int kt = 0; kt < 768; kt += 64) {
    f32x4 acc[2][2] = {};
#pragma unroll
    for (int ks = 0; ks < 2; ++ks) {
      int d0 = ks * 32 + lk * 8;
      bf16x8 a0 = ld_cvt8(Wr + (size_t)(wm + lr) * 64 + d0);
      bf16x8 a1 = ld_cvt8(Wr + (size_t)(wm + 16 + lr) * 64 + d0);
      bf16x8 b0 = ld_cvt8(Wq + (size_t)(kt + wn + lr) * 768 + h * 64 + d0);
      bf16x8 b1 = ld_cvt8(Wq + (size_t)(kt + wn + 16 + lr) * 768 + h * 64 + d0);
      acc[0][0] = MFMA16(a0, b0, acc[0][0]);
      acc[0][1] = MFMA16(a0, b1, acc[0][1]);
      acc[1][0] = MFMA16(a1, b0, acc[1][0]);
      acc[1][1] = MFMA16(a1, b1, acc[1][1]);
    }
#pragma unroll
    for (int mf = 0; mf < 2; ++mf)
#pragma unroll
      for (int nf = 0; nf < 2; ++nf) {
        int kcol = kt + wn + nf * 16 + lr;
#pragma unroll
        for (int reg = 0; reg < 4; ++reg) {
          int r = wm + mf * 16 + lk * 4 + reg;
          WqrT[(size_t)(h * 64 + r) * 768 + kcol] = f2bf(0.125f * acc[mf][nf][reg]);
        }
      }
  }
}

// ---------------------------------------------------------------------------
// K1: uniform projection GEMM, LDS-TILED bf16 (fixes round-8's gather
// latency AND round-6's conflicted scalar transposed staging).
// M=2048, K=768 (BK=64, 12 steps), N = 48 blocks of 64 (q,k,v,qr).
// Staging: coalesced 32B/thread global loads -> b128 LDS writes, no cvt.
// ---------------------------------------------------------------------------
__global__ __launch_bounds__(256) void k_qkv3(
    const short* __restrict__ xb, const short* __restrict__ WbT,
    const short* __restrict__ WqrT,
    const float* __restrict__ bq, const float* __restrict__ bk,
    const float* __restrict__ bv, const float* __restrict__ bqr,
    short* __restrict__ qkv, short* __restrict__ qrb, short* __restrict__ vT) {
  __shared__ short As[64 * 72];
  __shared__ short Bs[64 * 72];
  const int m0 = blockIdx.x * 64;
  const int nb = blockIdx.y;
  const int mat = nb / 12, h0 = nb % 12;
  const short* __restrict__ Bp =
      (mat < 3) ? WbT + (size_t)mat * WT_N + (size_t)(h0 * 64) * 768
                : WqrT + (size_t)(h0 * 64) * 768;
  const float* __restrict__ bias =
      (mat == 0) ? bq + h0 * 64 : (mat == 1) ? bk + h0 * 64
      : (mat == 2) ? bv + h0 * 64 : bqr + h0 * 64;
  const int t = threadIdx.x;
  const int w = t >> 6, lane = t & 63;
  const int wm = (w >> 1) * 32, wn = (w & 1) * 32;
  const int lr = lane & 15, lk = lane >> 4;
  const int sr = t >> 2, sc = (t & 3) * 16;    // staging row / col (16 elems)
  f32x4 acc[2][2] = {};
  for (int kk = 0; kk < 768; kk += 64) {
    {  // stage A: 64 rows x 64 k, 32B per thread
      const short* src = xb + (size_t)(m0 + sr) * 768 + kk + sc;
      *reinterpret_cast<bf16x8*>(&As[sr * 72 + sc])     = *reinterpret_cast<const bf16x8*>(src);
      *reinterpret_cast<bf16x8*>(&As[sr * 72 + sc + 8]) = *reinterpret_cast<const bf16x8*>(src + 8);
      const short* srb = Bp + (size_t)sr * 768 + kk + sc;
      *reinterpret_cast<bf16x8*>(&Bs[sr * 72 + sc])     = *reinterpret_cast<const bf16x8*>(srb);
      *reinterpret_cast<bf16x8*>(&Bs[sr * 72 + sc + 8]) = *reinterpret_cast<const bf16x8*>(srb + 8);
    }
    __syncthreads();
#pragma unroll
    for (int ks = 0; ks < 2; ++ks) {
      int k0 = ks * 32 + lk * 8;
      bf16x8 a0 = *reinterpret_cast<const bf16x8*>(&As[(wm + lr) * 72 + k0]);
      bf16x8 a1 = *reinterpret_cast<const bf16x8*>(&As[(wm + 16 + lr) * 72 + k0]);
      bf16x8 b0 = *reinterpret_cast<const bf16x8*>(&Bs[(wn + lr) * 72 + k0]);
      bf16x8 b1 = *reinterpret_cast<const bf16x8*>(&Bs[(wn + 16 + lr) * 72 + k0]);
      acc[0][0] = MFMA16(a0, b0, acc[0][0]);
      acc[0][1] = MFMA16(a0, b1, acc[0][1]);
      acc[1][0] = MFMA16(a1, b0, acc[1][0]);
      acc[1][1] = MFMA16(a1, b1, acc[1][1]);
    }
    __syncthreads();
  }
  const int b_ = m0 >> 9;
#pragma unroll
  for (int mf = 0; mf < 2; ++mf)
#pragma unroll
    for (int nf = 0; nf < 2; ++nf) {
      int d = wn + nf * 16 + lr;
      float bv_ = bias[d];
#pragma unroll
      for (int reg = 0; reg < 4; ++reg) {
        int i = (m0 + wm + mf * 16 + lk * 4 + reg) & 511;
        float val = acc[mf][nf][reg] + bv_;
        if (mat == 2) {
          vT[((size_t)(b_ * NH + h0) * HD + d) * S + i] = f2bf(val);
        } else if (mat == 3) {
          qrb[((size_t)(b_ * NH + h0) * S + i) * 64 + d] = f2bf(val);
        } else {
          qkv[(size_t)mat * QKV_N + (size_t)((b_ * NH + h0) * S + i) * HD + d] = f2bf(val);
        }
      }
    }
}

// ---------------------------------------------------------------------------
// K3: PURE qk scores -> f16 [b][i][h][j], no mask (mask applied in relsm).
// ---------------------------------------------------------------------------
__global__ __launch_bounds__(256) void k_qk(const short* __restrict__ q,
                                            const short* __restrict__ kmat,
                                            __half* __restrict__ sc) {
  const int j0 = blockIdx.x * 64, i0 = blockIdx.y * 64;
  const int bh = blockIdx.z;
  const int b = bh / NH, hh = bh % NH;
  const short* __restrict__ qp = q + (size_t)(bh * S) * HD;
  const short* __restrict__ kp = kmat + (size_t)(bh * S) * HD;
  const int t = threadIdx.x;
  const int w = t >> 6, lane = t & 63;
  const int wm = (w >> 1) * 32, wn = (w & 1) * 32;
  const int lr = lane & 15, lk = lane >> 4;
  f32x4 acc[2][2] = {};
#pragma unroll
  for (int ks = 0; ks < 2; ++ks) {
    int k0 = ks * 32 + lk * 8;
    bf16x8 a0 = *reinterpret_cast<const bf16x8*>(qp + (size_t)(i0 + wm + lr) * 64 + k0);
    bf16x8 a1 = *reinterpret_cast<const bf16x8*>(qp + (size_t)(i0 + wm + 16 + lr) * 64 + k0);
    bf16x8 b0 = *reinterpret_cast<const bf16x8*>(kp + (size_t)(j0 + wn + lr) * 64 + k0);
    bf16x8 b1 = *reinterpret_cast<const bf16x8*>(kp + (size_t)(j0 + wn + 16 + lr) * 64 + k0);
    acc[0][0] = MFMA16(a0, b0, acc[0][0]);
    acc[0][1] = MFMA16(a0, b1, acc[0][1]);
    acc[1][0] = MFMA16(a1, b0, acc[1][0]);
    acc[1][1] = MFMA16(a1, b1, acc[1][1]);
  }
#pragma unroll
  for (int mf = 0; mf < 2; ++mf)
#pragma unroll
    for (int nf = 0; nf < 2; ++nf) {
      int j = j0 + wn + nf * 16 + lr;
#pragma unroll
      for (int reg = 0; reg < 4; ++reg) {
        int i = i0 + wm + mf * 16 + lk * 4 + reg;
        sc[(((size_t)b * S + i) * NH + hh) * S + j] = __float2half(acc[mf][nf][reg] * 0.125f);
      }
    }
}

// ---------------------------------------------------------------------------
// K4: per (b,i): s = sc[h,j] + mask[j] + qr.rel^T; p = exp(min(s,80));
// den-reduce; probs bf16. Mask row staged once per block.
// ---------------------------------------------------------------------------
__global__ __launch_bounds__(256) void k_relsm(const short* __restrict__ qrb,
                                               const float* __restrict__ rel,
                                               const __half* __restrict__ sc,
                                               const float* __restrict__ graph,
                                               const float* __restrict__ endm,
                                               short* __restrict__ probs) {
  __shared__ short sq[16 * 520];
  __shared__ float mask_lds[512];
  __shared__ float den_lds[64];
  const int i = blockIdx.x, b = blockIdx.y;
  const int t = threadIdx.x;
  const int w = t >> 6, lane = t & 63;
  const int lr = lane & 15, fq = lane >> 4;
  {
    const short* src = reinterpret_cast<const short*>(sc + ((size_t)(b * S) + i) * NH * S);
    int hh = t >> 4, js = (t & 15) * 32;
    const short* sp = src + (size_t)hh * S + js;
    short* dp = &sq[hh * 520 + js];
#pragma unroll
    for (int c = 0; c < 4; ++c)
      *reinterpret_cast<bf16x8*>(dp + c * 8) = *reinterpret_cast<const bf16x8*>(sp + c * 8);
  }
  {
    int j = t * 2;
    float2 g = *reinterpret_cast<const float2*>(graph + ((size_t)b * S + i) * S + j);
    float2 e = *reinterpret_cast<const float2*>(endm + (size_t)b * S + j);
    mask_lds[j]     = (1.0f - g.x - e.x) * (-30000.0f);
    mask_lds[j + 1] = (1.0f - g.y - e.y) * (-30000.0f);
  }
  const int hA = (lr < NH) ? lr : 0;
  const short* qrow = qrb + ((size_t)(b * NH + hA) * S + i) * 64;
  bf16x8 a0 = *reinterpret_cast<const bf16x8*>(qrow + fq * 8);
  bf16x8 a1 = *reinterpret_cast<const bf16x8*>(qrow + 32 + fq * 8);
  const float* rp = rel + (((size_t)(b * S) + i) * S + (size_t)(w * 128 + lr)) * 64 + fq * 8;
  float p[8][4];
  float den[4] = {0.f, 0.f, 0.f, 0.f};
  f32x4 c0 = ld4nt(rp), c1 = ld4nt(rp + 4), c2 = ld4nt(rp + 32), c3 = ld4nt(rp + 36);
  __syncthreads();
#pragma unroll
  for (int tt = 0; tt < 8; ++tt) {
    f32x4 n0, n1, n2, n3;
    if (tt < 7) {
      const float* rn = rp + (size_t)(tt + 1) * 1024;
      n0 = ld4nt(rn); n1 = ld4nt(rn + 4); n2 = ld4nt(rn + 32); n3 = ld4nt(rn + 36);
    }
    bf16x8 b0 = cvt8(c0, c1), b1 = cvt8(c2, c3);
    f32x4 acc = {};
    acc = MFMA16(a0, b0, acc);
    acc = MFMA16(a1, b1, acc);
    const int j0 = w * 128 + tt * 16;
    const float mval = mask_lds[j0 + lr];
#pragma unroll
    for (int r = 0; r < 4; ++r) {
      int h = fq * 4 + r;
      float s = acc[r] + h2f(sq[h * 520 + j0 + lr]) + mval;
      float pe = __expf(fminf(s, 80.0f));
      den[r] += pe;
      p[tt][r] = pe;
    }
    if (tt < 7) { c0 = n0; c1 = n1; c2 = n2; c3 = n3; }
  }
#pragma unroll
  for (int r = 0; r < 4; ++r) {
    float d = den[r];
    d += __shfl_xor(d, 1); d += __shfl_xor(d, 2);
    d += __shfl_xor(d, 4); d += __shfl_xor(d, 8);
    den[r] = d;
  }
  if (lr == 0) {
#pragma unroll
    for (int r = 0; r < 4; ++r) den_lds[w * 16 + fq * 4 + r] = den[r];
  }
  __syncthreads();
  float invd[4];
#pragma unroll
  for (int r = 0; r < 4; ++r) {
    int h = fq * 4 + r;
    invd[r] = 1.0f / (den_lds[h] + den_lds[16 + h] + den_lds[32 + h] + den_lds[48 + h]);
  }
#pragma unroll
  for (int tt = 0; tt < 8; ++tt) {
    int j0 = w * 128 + tt * 16;
#pragma unroll
    for (int r = 0; r < 4; ++r) {
      int h = fq * 4 + r;
      if (h < NH)
        probs[((size_t)(b * NH + h) * S + i) * S + j0 + lr] = f2bf(p[tt][r] * invd[r]);
    }
  }
}

// ---------------------------------------------------------------------------
// K5: ctx = probs @ v via MFMA, LDS-free (vT[b,h,d,j]).
// ---------------------------------------------------------------------------
__global__ __launch_bounds__(256) void k_pv2(const short* __restrict__ probs,
                                             const short* __restrict__ vT,
                                             float* __restrict__ out) {
  const int i0 = blockIdx.x * 32;
  const int h = blockIdx.y, b = blockIdx.z;
  const short* __restrict__ pp  = probs + (size_t)((b * NH + h) * S) * S;
  const short* __restrict__ vtp = vT + (size_t)((b * NH + h) * HD) * S;
  const int t = threadIdx.x;
  const int w = t >> 6, lane = t & 63;
  const int wm = (w >> 1) * 16, wn = (w & 1) * 32;
  const int lr = lane & 15, lk = lane >> 4;
  f32x4 acc[2] = {};
#pragma unroll
  for (int j0 = 0; j0 < S; j0 += 64) {
#pragma unroll
    for (int ks = 0; ks < 2; ++ks) {
      int k0 = j0 + ks * 32 + lk * 8;
      bf16x8 a0 = *reinterpret_cast<const bf16x8*>(pp + (size_t)(i0 + wm + lr) * S + k0);
      bf16x8 b0 = *reinterpret_cast<const bf16x8*>(vtp + (size_t)(wn + lr) * S + k0);
      bf16x8 b1 = *reinterpret_cast<const bf16x8*>(vtp + (size_t)(wn + 16 + lr) * S + k0);
      acc[0] = MFMA16(a0, b0, acc[0]);
      acc[1] = MFMA16(a0, b1, acc[1]);
    }
  }
#pragma unroll
  for (int nf = 0; nf < 2; ++nf) {
    int d = wn + nf * 16 + lr;
#pragma unroll
    for (int reg = 0; reg < 4; ++reg) {
      int i = i0 + wm + lk * 4 + reg;
      out[((size_t)(b * S) + i) * HID + h * 64 + d] = acc[nf][reg];
    }
  }
}

// ---------------------------------------------------------------------------
extern "C" void kernel_launch(void* const* d_in, const int* in_sizes, int n_in,
                              void* d_out, int out_size, void* d_ws, size_t ws_size,
                              hipStream_t stream) {
  const float* x     = (const float*)d_in[0];
  const float* graph = (const float*)d_in[1];
  const float* endm  = (const float*)d_in[2];
  const float* rel   = (const float*)d_in[3];
  const float* Wq = (const float*)d_in[4];  const float* bq = (const float*)d_in[5];
  const float* Wk = (const float*)d_in[6];  const float* bk = (const float*)d_in[7];
  const float* Wv = (const float*)d_in[8];  const float* bv = (const float*)d_in[9];
  const float* Wr = (const float*)d_in[10]; // br dropped: softmax-invariant

  short* xb   = (short*)d_ws;                    // bf16 x   [2048][768]
  short* WbT  = xb + XB_N;                       // bf16 W^T x3
  short* WqrT = WbT + 3 * WT_N;                  // bf16 combined qr weight
  float* bqr  = (float*)(WqrT + WT_N);
  short* qb   = (short*)(bqr + 768);
  short* kb   = qb + QKV_N;
  short* vTb  = kb + QKV_N;                      // v transposed [b][h][d][j]
  short* qrb  = vTb + QKV_N;
  __half* scores = (__half*)(qrb + QKV_N);       // f16, [b][i][h][j] (unmasked)
  short* probs   = (short*)(scores + SCORES_N);  // bf16, [b][h][i][j]
  const size_t need = (size_t)(XB_N + 4 * WT_N) * 2 + 768 * 4 +
                      (size_t)4 * QKV_N * 2 + SCORES_N * 2 + SCORES_N * 2;
  if (ws_size < need) return;

  k_prep<<<dim3(1212), 256, 0, stream>>>(x, Wq, Wk, Wv, Wr, bq, xb, WbT, WqrT, bqr);
  k_qkv3<<<dim3(32, 48), 256, 0, stream>>>(xb, WbT, WqrT, bq, bk, bv, bqr, qb, qrb, vTb);
  k_qk<<<dim3(8, 8, B * NH), 256, 0, stream>>>(qb, kb, scores);
  k_relsm<<<dim3(S, B), 256, 0, stream>>>(qrb, rel, scores, graph, endm, probs);
  k_pv2<<<dim3(16, NH, B), 256, 0, stream>>>(probs, vTb, (float*)d_out);
}